// Round 1
// baseline (2287.089 us; speedup 1.0000x reference)
//
#include <hip/hip_runtime.h>
#include <math.h>

// clDice loss, fused temporal-blocked skeletonization.
// Planes: 16 batch x 2 ch = 32 per tensor; tensor 0 = sigmoid(logits), 1 = targets.
// Each block: 64x64 output tile + halo 11 staged in LDS, 10 erode/dilate iters,
// accumulates sum(skel) and sum(skel*other) -> 2 atomics into d_ws.

#define HH 1024
#define WW 1024
#define TILE 64
#define HALO 11
#define REG (TILE + 2*HALO)      // 86
#define RSZ (REG*REG)            // 7396
#define ER  84                   // fixed erode region (rings 0..10)
#define ERSZ (ER*ER)             // 7056

__global__ __launch_bounds__(256, 2)
void skel_kernel(const float* __restrict__ logits,
                 const float* __restrict__ targets,
                 float* __restrict__ sums)
{
    __shared__ float buf[2][RSZ];
    __shared__ float red[8];

    const int t    = threadIdx.x;
    const int tile = blockIdx.x;
    const int job  = blockIdx.y;
    const int tensor = job >> 5;          // 0: skeleton of pred, 1: skeleton of target
    const int plane  = job & 31;          // b*2 + c
    const size_t planeOff = (size_t)plane * (HH * WW);

    const int ty0 = (tile >> 4) * TILE - HALO;   // region origin (global coords)
    const int tx0 = (tile & 15) * TILE - HALO;

    const float* __restrict__ src  = tensor ? targets : logits;
    const float* __restrict__ osrc = tensor ? logits  : targets;

    // ---- stage source region into LDS (out-of-image -> +inf = erode identity)
    for (int i = t; i < RSZ; i += 256) {
        int y = i / REG;
        int x = i - y * REG;
        int gy = ty0 + y, gx = tx0 + x;
        float v = INFINITY;
        if ((unsigned)gy < HH && (unsigned)gx < WW) {
            v = src[planeOff + (size_t)gy * WW + gx];
            if (!tensor) v = 1.0f / (1.0f + __expf(-v));   // sigmoid for pred
        }
        buf[0][i] = v;
    }

    // ---- load "other" tensor for interior pixels (16 per thread, coalesced)
    float other[16];
#pragma unroll
    for (int j = 0; j < 16; ++j) {
        int p = t + j * 256;
        int y = p >> 6, x = p & 63;
        float v = osrc[planeOff + (size_t)(ty0 + HALO + y) * WW + (tx0 + HALO + x)];
        if (tensor) v = 1.0f / (1.0f + __expf(-v));        // other = pred for gt-skel
        other[j] = v;
    }

    float sumS = 0.f, sumP = 0.f;
    __syncthreads();

    for (int it = 0; it < 10; ++it) {
        const float* cur = buf[it & 1];        // img1
        float*       nxt = buf[(it & 1) ^ 1];  // E

        // ---- erode: E = min over 5-point cross. Fixed region rings 0..10.
        // Outer rings get stale data late in the loop but provably never
        // contaminate rings <=1, which is all the dilate/skel path reads.
        for (int i = t; i < ERSZ; i += 256) {
            int y = i / ER;
            int x = i - y * ER;
            int by = y + 1, bx = x + 1;        // buffer coords in [1,85)
            int idx = by * REG + bx;
            float c  = cur[idx];
            float up = cur[idx - REG];
            float dn = cur[idx + REG];
            float lf = cur[idx - 1];
            float rt = cur[idx + 1];
            float e = fminf(fminf(fminf(up, dn), fminf(lf, rt)), c);
            int gy = ty0 + by, gx = tx0 + bx;
            if (!((unsigned)gy < HH && (unsigned)gx < WW)) e = INFINITY;  // keep OOB = +inf
            nxt[idx] = e;
        }
        __syncthreads();

        // ---- dilate(E) 3x3 on interior + skel contribution
#pragma unroll
        for (int j = 0; j < 16; ++j) {
            int p = t + j * 256;
            int y = (p >> 6) + HALO;
            int x = (p & 63) + HALO;
            int idx = y * REG + x;
            int gy = ty0 + y, gx = tx0 + x;    // interior pixels: always in image
            bool yu = gy > 0, yd = gy < HH - 1, xl = gx > 0, xr = gx < WW - 1;
            // unconditional LDS reads (always in-buffer), predicated to -inf if OOB-of-image
            float c  = nxt[idx];
            float n0 = nxt[idx - REG];
            float n1 = nxt[idx + REG];
            float n2 = nxt[idx - 1];
            float n3 = nxt[idx + 1];
            float n4 = nxt[idx - REG - 1];
            float n5 = nxt[idx - REG + 1];
            float n6 = nxt[idx + REG - 1];
            float n7 = nxt[idx + REG + 1];
            float m = c;
            m = fmaxf(m, yu         ? n0 : -INFINITY);
            m = fmaxf(m, yd         ? n1 : -INFINITY);
            m = fmaxf(m, xl         ? n2 : -INFINITY);
            m = fmaxf(m, xr         ? n3 : -INFINITY);
            m = fmaxf(m, (yu && xl) ? n4 : -INFINITY);
            m = fmaxf(m, (yu && xr) ? n5 : -INFINITY);
            m = fmaxf(m, (yd && xl) ? n6 : -INFINITY);
            m = fmaxf(m, (yd && xr) ? n7 : -INFINITY);
            float contrib = fmaxf(cur[idx] - m, 0.f);
            sumS += contrib;
            sumP += other[j] * contrib;
        }
        __syncthreads();
    }

    // ---- block reduce -> 2 atomics
#pragma unroll
    for (int off = 32; off > 0; off >>= 1) {
        sumS += __shfl_down(sumS, off, 64);
        sumP += __shfl_down(sumP, off, 64);
    }
    int wid = t >> 6, lane = t & 63;
    if (lane == 0) { red[wid * 2] = sumS; red[wid * 2 + 1] = sumP; }
    __syncthreads();
    if (t == 0) {
        float s = red[0] + red[2] + red[4] + red[6];
        float p = red[1] + red[3] + red[5] + red[7];
        int base = plane * 4 + (tensor ? 2 : 0);
        // slots: 0 = sum(skel_pred), 1 = sum(skel_pred*target),
        //        2 = sum(skel_gt),   3 = sum(skel_gt*pred)
        atomicAdd(&sums[base],     s);
        atomicAdd(&sums[base + 1], p);
    }
}

__global__ void finalize_kernel(const float* __restrict__ s4, float* __restrict__ out)
{
    __shared__ float cl[32];
    int p = threadIdx.x;
    if (p < 32) {
        const float* s = s4 + p * 4;
        float tprec = s[1] / (s[0] + 1e-6f);
        float tsens = s[3] / (s[2] + 1e-6f);
        cl[p] = 2.f * tprec * tsens / (tprec + tsens + 1e-6f);
    }
    __syncthreads();
    if (p == 0) {
        float a = 0.f, v = 0.f;
        for (int b = 0; b < 16; ++b) { a += cl[b * 2]; v += cl[b * 2 + 1]; }
        out[0] = 1.f - 0.5f * (a / 16.f + v / 16.f);
    }
}

extern "C" void kernel_launch(void* const* d_in, const int* in_sizes, int n_in,
                              void* d_out, int out_size, void* d_ws, size_t ws_size,
                              hipStream_t stream)
{
    const float* logits  = (const float*)d_in[0];
    const float* targets = (const float*)d_in[1];
    float* out  = (float*)d_out;
    float* sums = (float*)d_ws;

    // zero the 32 planes x 4 accumulators (ws is poisoned before every launch)
    hipMemsetAsync(d_ws, 0, 32 * 4 * sizeof(float), stream);

    dim3 grid(256, 64);   // 16x16 tiles  x  (32 planes * 2 tensors)
    skel_kernel<<<grid, 256, 0, stream>>>(logits, targets, sums);
    finalize_kernel<<<1, 64, 0, stream>>>(sums, out);
}

// Round 2
// 1061.315 us; speedup vs baseline: 2.1550x; 2.1550x over previous
//
#include <hip/hip_runtime.h>
#include <math.h>

// clDice loss via register-resident temporal cascade.
// All 10 soft_skel iterations run as a systolic pipeline of erode stages,
// swept top->bottom. Per lane: 4 columns (float4), per stage a 3-row rolling
// register window. No LDS, no barriers; horizontal halo via __shfl.
//
// Geometry: wave covers 256 cols (lane*4 + 232*s - 12), owns 232 [s*232,..).
// Col-OOB is lane-uniform and loads stay 16B-aligned by construction.
// 5 col-strips x 8 row-strips(128 rows, 11-row warmup/drain) x 64 jobs
// (= 2 tensors x 16 batch x 2 ch) = 2560 waves, 640 blocks of 256.

#define HH 1024
#define WW 1024
#define OWN_W 232
#define VROWS 128
#define NMACRO 51   // 153 steps = 128 + 11 warmup + 12 drain + pad to x3

#define MOD3(x) ((((x) % 3) + 3) % 3)

__device__ __forceinline__ float4 f4s(float v) { float4 r; r.x = v; r.y = v; r.z = v; r.w = v; return r; }
__device__ __forceinline__ float sigm(float x) { return __builtin_amdgcn_rcpf(1.0f + __expf(-x)); }
__device__ __forceinline__ float min5(float a, float b, float c, float d, float e) {
    return fminf(fminf(fminf(a, b), fminf(c, d)), e);
}
__device__ __forceinline__ float max3(float a, float b, float c) {
    return fmaxf(fmaxf(a, b), c);
}

__global__ __launch_bounds__(256, 2)
void skel_kernel(const float* __restrict__ logits,
                 const float* __restrict__ targets,
                 float* __restrict__ sums)
{
    const int lane = threadIdx.x & 63;
    const int gwid = __builtin_amdgcn_readfirstlane(blockIdx.x * 4 + (threadIdx.x >> 6));
    const int job  = gwid / 40;          // 0..63
    const int rem  = gwid - job * 40;
    const int s    = rem % 5;            // col strip
    const int v    = rem / 5;            // row strip
    const int tensor = job >> 5;         // 0: skel(pred), 1: skel(target)
    const int plane  = job & 31;
    const size_t planeOff = (size_t)plane * (HH * WW);
    const float* __restrict__ src  = tensor ? targets : logits;   // skel source
    const float* __restrict__ osrc = tensor ? logits  : targets;  // multiplied tensor
    const bool sEdge = (s == 0) || (s == 4);

    const int colBase = OWN_W * s - 12 + lane * 4;
    const bool colOOB = (colBase < 0) || (colBase > WW - 4);      // whole-lane by construction
    const int colC = colBase < 0 ? 0 : (colBase > WW - 4 ? WW - 4 : colBase);
    const int y0 = v * VROWS;
    const int rBase = y0 - 11;

    const int ownHi = (OWN_W * (s + 1) < WW) ? OWN_W * (s + 1) : WW;
    const bool ownedLane = (colBase >= OWN_W * s) && (colBase < ownHi);

    // E[k][slot]: stage-k erode output, 3-row rolling window. Row y lives at
    // slot (y - rBase) mod 3 (stage-independent). E[0] = source image window.
    float4 E[11][3];
#pragma unroll
    for (int k = 0; k < 11; ++k)
#pragma unroll
        for (int j = 0; j < 3; ++j) E[k][j] = f4s(INFINITY);

    // shift-register ring of 'other' rows; at macro m, slot j holds row
    // (y0 - 23 + 3m + j). Stage k, phase p reads slot 10+p-k (row = dilate row).
    float4 oring[15];
#pragma unroll
    for (int j = 0; j < 15; ++j) oring[j] = f4s(0.f);

    float4 sumS = f4s(0.f), sumP = f4s(0.f);

    auto loadImg = [&](int row) -> float4 {
        float4 x;
        if ((unsigned)row < HH) {
            const float* p = src + planeOff + (size_t)row * WW + colC;
            x = *(const float4*)p;
            if (!tensor) { x.x = sigm(x.x); x.y = sigm(x.y); x.z = sigm(x.z); x.w = sigm(x.w); }
            if (sEdge && colOOB) x = f4s(INFINITY);
        } else {
            x = f4s(INFINITY);   // out-of-image rows: erode identity
        }
        return x;
    };
    auto loadOther = [&](int row) -> float4 {
        int rc = row < 0 ? 0 : (row > HH - 1 ? HH - 1 : row);
        const float* p = osrc + planeOff + (size_t)rc * WW + colC;
        float4 x = *(const float4*)p;
        if (tensor) { x.x = sigm(x.x); x.y = sigm(x.y); x.z = sigm(x.z); x.w = sigm(x.w); }
        return x;
    };

    float4 nextImg = loadImg(rBase);   // prefetch row for t=0

#pragma unroll 1
    for (int m = 0; m < NMACRO; ++m) {
        // ring shift + 3 new 'other' rows (consumed >=4 steps later)
#pragma unroll
        for (int j = 0; j < 12; ++j) oring[j] = oring[j + 3];
#pragma unroll
        for (int j = 0; j < 3; ++j) oring[12 + j] = loadOther(rBase + 3 * m + j);

#pragma unroll
        for (int p = 0; p < 3; ++p) {
            const int r = rBase + 3 * m + p;     // img row fed this step
            const float4 img = nextImg;
            nextImg = loadImg(r + 1);            // prefetch next step's row

            // ---------- Pass D: dilate stage k at row yd = r-k-2 (pre-update windows) ----------
#pragma unroll
            for (int k = 1; k <= 10; ++k) {
                const int yd = r - k - 2;
                if (yd >= y0 && yd < y0 + VROWS) {      // wave-uniform ownership guard
                    const float4 a = E[k][MOD3(p - k)];       // row yd-1
                    const float4 b = E[k][MOD3(p - k + 1)];   // row yd
                    const float4 c = E[k][MOD3(p - k + 2)];   // row yd+1
                    float4 vm;
                    if (yd == 0) {                // image top: exclude row -1
                        vm.x = fmaxf(b.x, c.x); vm.y = fmaxf(b.y, c.y);
                        vm.z = fmaxf(b.z, c.z); vm.w = fmaxf(b.w, c.w);
                    } else if (yd == HH - 1) {    // image bottom: exclude row 1024
                        vm.x = fmaxf(a.x, b.x); vm.y = fmaxf(a.y, b.y);
                        vm.z = fmaxf(a.z, b.z); vm.w = fmaxf(a.w, b.w);
                    } else {
                        vm.x = max3(a.x, b.x, c.x); vm.y = max3(a.y, b.y, c.y);
                        vm.z = max3(a.z, b.z, c.z); vm.w = max3(a.w, b.w, c.w);
                    }
                    if (sEdge) { if (colOOB) vm = f4s(-INFINITY); }  // col truncation at image edge
                    const float vl = __shfl_up(vm.w, 1, 64);
                    const float vr = __shfl_down(vm.x, 1, 64);
                    float4 h;
                    h.x = max3(vl,   vm.x, vm.y);
                    h.y = max3(vm.x, vm.y, vm.z);
                    h.z = max3(vm.y, vm.z, vm.w);
                    h.w = max3(vm.z, vm.w, vr);
                    const float4 io = E[k - 1][MOD3(p - k + 1)];  // img_k at row yd
                    float4 ct;
                    ct.x = fmaxf(io.x - h.x, 0.f);
                    ct.y = fmaxf(io.y - h.y, 0.f);
                    ct.z = fmaxf(io.z - h.z, 0.f);
                    ct.w = fmaxf(io.w - h.w, 0.f);
                    const float4 ot = oring[10 + p - k];
                    sumS.x += ct.x; sumS.y += ct.y; sumS.z += ct.z; sumS.w += ct.w;
                    sumP.x = fmaf(ot.x, ct.x, sumP.x);
                    sumP.y = fmaf(ot.y, ct.y, sumP.y);
                    sumP.z = fmaf(ot.z, ct.z, sumP.z);
                    sumP.w = fmaf(ot.w, ct.w, sumP.w);
                }
            }

            // ---------- Pass E: erode cascade, stage k emits row r-k ----------
            E[0][MOD3(p)] = img;
            float4 np_ = img;    // new row of stage k-1 (row r-k+1 when at stage k)
#pragma unroll
            for (int k = 1; k <= 10; ++k) {
                const float4 A = E[k - 1][MOD3(p - k + 2)];  // row r-k-1 (up)
                const float4 B = E[k - 1][MOD3(p - k)];      // row r-k   (center)
                const float4 C = np_;                        // row r-k+1 (down)
                const float bl = __shfl_up(B.w, 1, 64);
                const float br = __shfl_down(B.x, 1, 64);
                float4 ne;
                ne.x = min5(A.x, C.x, bl,  B.y, B.x);
                ne.y = min5(A.y, C.y, B.x, B.z, B.y);
                ne.z = min5(A.z, C.z, B.y, B.w, B.z);
                ne.w = min5(A.w, C.w, B.z, br,  B.w);
                const int yN = r - k;
                if ((unsigned)yN >= HH) {        // out-of-image rows stay +inf
                    ne = f4s(INFINITY);
                } else if (sEdge) {
                    if (colOOB) ne = f4s(INFINITY);  // out-of-image cols stay +inf
                }
                E[k][MOD3(p - k)] = ne;
                np_ = ne;
            }
        }
    }

    // ---------- reduce: mask unowned lanes, wave-reduce, 2 atomics ----------
    if (!ownedLane) { sumS = f4s(0.f); sumP = f4s(0.f); }
    float aS = sumS.x + sumS.y + sumS.z + sumS.w;
    float aP = sumP.x + sumP.y + sumP.z + sumP.w;
#pragma unroll
    for (int off = 32; off > 0; off >>= 1) {
        aS += __shfl_down(aS, off, 64);
        aP += __shfl_down(aP, off, 64);
    }
    if (lane == 0) {
        const int base = plane * 4 + tensor * 2;
        atomicAdd(&sums[base],     aS);   // sum(skel)
        atomicAdd(&sums[base + 1], aP);   // sum(skel * other)
    }
}

__global__ void finalize_kernel(const float* __restrict__ s4, float* __restrict__ out)
{
    __shared__ float cl[32];
    int p = threadIdx.x;
    if (p < 32) {
        const float* s = s4 + p * 4;
        float tprec = s[1] / (s[0] + 1e-6f);
        float tsens = s[3] / (s[2] + 1e-6f);
        cl[p] = 2.f * tprec * tsens / (tprec + tsens + 1e-6f);
    }
    __syncthreads();
    if (p == 0) {
        float a = 0.f, vch = 0.f;
        for (int b = 0; b < 16; ++b) { a += cl[b * 2]; vch += cl[b * 2 + 1]; }
        out[0] = 1.f - 0.5f * (a / 16.f + vch / 16.f);
    }
}

extern "C" void kernel_launch(void* const* d_in, const int* in_sizes, int n_in,
                              void* d_out, int out_size, void* d_ws, size_t ws_size,
                              hipStream_t stream)
{
    const float* logits  = (const float*)d_in[0];
    const float* targets = (const float*)d_in[1];
    float* out  = (float*)d_out;
    float* sums = (float*)d_ws;

    hipMemsetAsync(d_ws, 0, 32 * 4 * sizeof(float), stream);

    // 2560 waves = 5 col-strips x 8 row-strips x 64 jobs; 4 waves per block
    skel_kernel<<<640, 256, 0, stream>>>(logits, targets, sums);
    finalize_kernel<<<1, 64, 0, stream>>>(sums, out);
}